// Round 10
// baseline (697.621 us; speedup 1.0000x reference)
//
#include <hip/hip_runtime.h>
#include <math.h>

// AAModel round 10: ATOMIC-FREE conv via two-phase message/gather.
// Rounds 3-9 evidence: four different conv structures all plateau at
// 192-268us regardless of occupancy/VGPR/W2-traffic -> common external
// floor suspected = 6.5M scattered global f32 atomics per conv
// back-pressuring L2 and inflating W2 load latency.
// This round: conv writes per-edge messages coalesced (no atomics);
// CSR (scan+place, us-scale) + gather kernels do the segment-mean.
// Conv tile loop is byte-identical to round 9 (single-variable change).

constexpr float SQ3f = 1.7320508075688772f;
constexpr float INV1 = 0.14433756729740643f;  // 1/sqrt(48)
constexpr float NAc  = 0.10206207261596575f;  // 1/sqrt(2*48)
constexpr float NBc  = 0.22360679774997896f;  // 1/sqrt(2*10)
constexpr float C20  = 0.22360679774997896f;  // 1/sqrt(20)
constexpr float RATIO= 1.2649110640673518f;   // (NBc/sqrt3)/NAc
constexpr float DSP  = 30.0f/31.0f;
constexpr float GCOEF= -0.5f/(DSP*DSP);

typedef __attribute__((ext_vector_type(8))) short bf16x8;
typedef __attribute__((ext_vector_type(4))) float f32x4;

__device__ __forceinline__ unsigned short f2bf(float x) {
    unsigned u = __builtin_bit_cast(unsigned, x);
    u += 0x7fffu + ((u >> 16) & 1u);     // RNE
    return (unsigned short)(u >> 16);
}
__device__ __forceinline__ float bf2f(unsigned short h) {
    return __builtin_bit_cast(float, ((unsigned)h) << 16);
}

// tile/lane-slot -> original W2 column (or -1 = padding lane)
__device__ __forceinline__ int colmap(int layer, int t, int lm) {
    if (layer == 0) return t*16 + lm;                           // W1 identity
    if (layer == 1) {
        if (t < 144) { const int og=t/48, i=t-og*48; return i*48 + og*16 + lm; }      // w00
        const int i = t-144; return (lm<10) ? 2304 + i*10 + lm : -1;                  // w01
    }
    if (t < 144) { const int og=t/48, i=t-og*48; return i*48 + og*16 + lm; }          // w00
    if (t < 174) { const int s=t-144, og=s/10, i=s-og*10; return 2884 + i*48 + og*16 + lm; } // w11s
    if (t < 222) { const int i=t-174; return (lm<10) ? 2304 + i*10 + lm : -1; }       // w01
    if (t < 232) { const int i=t-222; return (lm<10) ? 2784 + i*10 + lm : -1; }       // w10
    { const int i=t-232; return (lm<10) ? 3364 + i*10 + lm : -1; }                    // w11p
}

__global__ __launch_bounds__(256)
void cvt_swz(const float* __restrict__ W, const float* __restrict__ bias,
             short* __restrict__ Wsw, int ncol, int ntile, int layer)
{
    const int gid = blockIdx.x*256 + threadIdx.x;
    const int g = gid >> 6, lane = gid & 63;
    if (g >= ntile*5) return;
    const int tile = g/5, ks = g - tile*5;
    const int c  = colmap(layer, tile, lane & 15);
    const int k0 = ks*32 + (lane >> 4)*8;
    union { uint4 u4; unsigned short h[8]; } pk;
    #pragma unroll
    for (int j=0;j<8;j++) {
        const int k = k0 + j;
        float v = 0.f;
        if (c >= 0) {
            if (k < 144)       v = W[(size_t)k*ncol + c];
            else if (k == 144) v = bias[c];
        }
        pk.h[j] = f2bf(v);
    }
    *(uint4*)&Wsw[((size_t)g*64 + lane)*8] = pk.u4;
}

// ----------------------------------------------------------------------------
__global__ __launch_bounds__(256)
void edge_kernel(const float* __restrict__ pos, const float* __restrict__ sigma,
                 const int* __restrict__ ei,
                 const float* __restrict__ W1, const float* __restrict__ b1,
                 const float* __restrict__ W2, const float* __restrict__ b2,
                 float* __restrict__ edge_emb, float* __restrict__ sh1buf,
                 int* __restrict__ deg, int E)
{
    __shared__ float inl[4][64];
    __shared__ float hidl[4][48];
    const int w    = threadIdx.x >> 6;
    const int lane = threadIdx.x & 63;
    const int e    = blockIdx.x*4 + w;
    const bool valid = (e < E);
    const int ec = valid ? e : 0;
    const int src = ei[ec], dst = ei[E+ec];
    const float vx = pos[dst*3+0]-pos[src*3+0];
    const float vy = pos[dst*3+1]-pos[src*3+1];
    const float vz = pos[dst*3+2]-pos[src*3+2];
    const float d  = sqrtf(vx*vx+vy*vy+vz*vz);
    const float si = SQ3f/(d+1e-8f);
    const float s0 = vx*si, s1 = vy*si, s2 = vz*si;
    if (lane < 32) {
        inl[w][lane] = sigma[src*32+lane];
    } else {
        const float off  = (float)(lane-32)*DSP;
        const float diff = d - off;
        inl[w][lane] = expf(GCOEF*diff*diff);
    }
    __syncthreads();
    if (lane < 48) {
        float a = b1[lane];
        #pragma unroll 8
        for (int j=0;j<64;j++) a = fmaf(inl[w][j], W1[j*48+lane], a);
        hidl[w][lane] = fmaxf(a, 0.f);
    }
    __syncthreads();
    if (valid) {
        if (lane < 48) {
            float a = b2[lane];
            #pragma unroll 8
            for (int j=0;j<48;j++) a = fmaf(hidl[w][j], W2[j*48+lane], a);
            edge_emb[e*48+lane] = a;
        }
        if (lane == 0) atomicAdd(&deg[dst], 1);
        if (lane < 3)  sh1buf[e*4+lane] = (lane==0)?s0:((lane==1)?s1:s2);
    }
}

// ----------------------------------------------------------------------------
// CSR build: single-block scan of deg -> rowptr/cursor; then edge placement.
// ----------------------------------------------------------------------------
__global__ __launch_bounds__(1024)
void scan_kernel(const int* __restrict__ deg, int* __restrict__ rowptr,
                 int* __restrict__ cursor, int Nn)
{
    __shared__ int part[1024];
    const int t = threadIdx.x;
    const int chunk = (Nn + 1023)/1024;
    const int base = t*chunk;
    int s = 0;
    for (int i=0;i<chunk;i++) { const int n=base+i; if (n<Nn) s += deg[n]; }
    part[t] = s;
    __syncthreads();
    for (int off=1; off<1024; off<<=1) {
        const int v = (t>=off) ? part[t-off] : 0;
        __syncthreads();
        part[t] += v;
        __syncthreads();
    }
    int run = part[t] - s;   // exclusive prefix of this thread's chunk
    for (int i=0;i<chunk;i++) {
        const int n=base+i;
        if (n<Nn) { rowptr[n]=run; cursor[n]=run; run += deg[n]; }
    }
    if (t==0) rowptr[Nn] = part[1023];
}

__global__ __launch_bounds__(256)
void place_kernel(const int* __restrict__ ei, int* __restrict__ cursor,
                  int* __restrict__ csr, int E)
{
    const int e = blockIdx.x*256 + threadIdx.x;
    if (e >= E) return;
    const int dst = ei[E+e];
    const int slot = atomicAdd(&cursor[dst], 1);
    csr[slot] = e;
}

// ----------------------------------------------------------------------------
__device__ __forceinline__ void load_bfrag(const short* __restrict__ Wsw,
                                           int tile, int lane, bf16x8 (&b)[5]) {
    #pragma unroll
    for (int ks=0; ks<5; ks++)
        b[ks] = *(const bf16x8*)&Wsw[((size_t)(tile*5+ks)*64 + lane)*8];
}

// ----------------------------------------------------------------------------
template<int LAYER>
__global__ __launch_bounds__(256)
void conv_kernel(const float* __restrict__ edge_emb, const float* __restrict__ sh1buf,
                 const int* __restrict__ ei,
                 const float* __restrict__ sin_, const float* __restrict__ vin,
                 const short* __restrict__ W1sw, const short* __restrict__ W2sw,
                 float* __restrict__ msg, int E)
{
    constexpr int NT = (LAYER==1) ? 192 : 242;
    constexpr int NG = NT/2;                 // 2-tile stage groups
    constexpr int ST = (LAYER==1) ? 78 : 108;

    // pool: ea (24KB, swizzled bf16) -> hid (20KB) -> W2 stage dbuf (2x10KB)
    __shared__ __align__(16) short pool[64*192];
    __shared__ __align__(16) unsigned short xsTb[48][64];   // bf16 xs, [chan][edge]
    __shared__ float sh1l[64][4];
    __shared__ int   srcl[64], dstl[64];
    __shared__ __align__(16) float xvT[LAYER==2 ? 30 : 1][64];
    __shared__ __align__(16) float uT [LAYER==2 ? 10 : 1][64];
    __shared__ __align__(16) float cvT[LAYER==2 ? 30 : 1][64];

    const int t  = threadIdx.x;
    const int eb = blockIdx.x * 64;

    if (t < 64) {
        const int ge = eb + t; const int gc = (ge < E) ? ge : (E-1);
        srcl[t] = ei[gc]; dstl[t] = ei[E+gc];
    }
    {
        const int e = t >> 2, k = t & 3;
        const int ge = eb + e; const int gc = (ge<E)?ge:(E-1);
        sh1l[e][k] = sh1buf[gc*4 + k];
    }
    __syncthreads();

    // ---- stage ea -> bf16 swizzled pool (+ bf16 xsT fill)
    for (int p = t; p < 64*24; p += 256) {
        const int m = p / 24, s = p - m*24;
        const int k0 = s*8;
        float vals[8] = {0.f,0.f,0.f,0.f,0.f,0.f,0.f,0.f};
        if (k0 < 48) {
            const int ge = eb + m; const int gc = (ge<E)?ge:(E-1);
            const float4 a = *(const float4*)&edge_emb[gc*48 + k0];
            const float4 b = *(const float4*)&edge_emb[gc*48 + k0 + 4];
            vals[0]=a.x; vals[1]=a.y; vals[2]=a.z; vals[3]=a.w;
            vals[4]=b.x; vals[5]=b.y; vals[6]=b.z; vals[7]=b.w;
        } else if (k0 < 96) {
            const float4 a = *(const float4*)&sin_[srcl[m]*48 + (k0-48)];
            const float4 b = *(const float4*)&sin_[srcl[m]*48 + (k0-48) + 4];
            vals[0]=a.x; vals[1]=a.y; vals[2]=a.z; vals[3]=a.w;
            vals[4]=b.x; vals[5]=b.y; vals[6]=b.z; vals[7]=b.w;
        } else if (k0 < 144) {
            const float4 a = *(const float4*)&sin_[dstl[m]*48 + (k0-96)];
            const float4 b = *(const float4*)&sin_[dstl[m]*48 + (k0-96) + 4];
            vals[0]=a.x; vals[1]=a.y; vals[2]=a.z; vals[3]=a.w;
            vals[4]=b.x; vals[5]=b.y; vals[6]=b.z; vals[7]=b.w;
        } else if (k0 == 144) {
            vals[0] = 1.f;                       // bias row for GEMM1
        }
        union { uint4 u4; unsigned short h[8]; } pk;
        #pragma unroll
        for (int j=0;j<8;j++) pk.h[j] = f2bf(vals[j]);
        *(uint4*)&pool[m*192 + ((s ^ (m&7))*8)] = pk.u4;
        if (k0 >= 48 && k0 < 96) {
            #pragma unroll
            for (int j=0;j<8;j++) xsTb[k0-48+j][m] = pk.h[j];
        }
    }
    if (LAYER==2) {
        for (int p=t; p<640; p+=256) {
            const int i = p >> 6, e = p & 63;
            const float x0 = vin[srcl[e]*30 + i*3+0];
            const float x1 = vin[srcl[e]*30 + i*3+1];
            const float x2 = vin[srcl[e]*30 + i*3+2];
            const float h0=sh1l[e][0], h1=sh1l[e][1], h2=sh1l[e][2];
            xvT[i*3+0][e]=x0; xvT[i*3+1][e]=x1; xvT[i*3+2][e]=x2;
            uT[i][e] = x0*h0 + x1*h1 + x2*h2;
            cvT[i*3+0][e] = x1*h2 - x2*h1;
            cvT[i*3+1][e] = x2*h0 - x0*h2;
            cvT[i*3+2][e] = x0*h1 - x1*h0;
        }
    }
    __syncthreads();

    const int wv = t >> 6, lane = t & 63;
    const int lm = lane & 15, lk = lane >> 4, lk4 = lk*4;

    // ---- GEMM1 in two M-halves: hid = relu(ea @ W1)
    f32x4 aa[3][2], ab[3][2];
    {
        bf16x8 af[2][5];
        #pragma unroll
        for (int mt=0; mt<2; mt++) {
            const int m = mt*16 + lm;
            #pragma unroll
            for (int ks=0; ks<5; ks++)
                af[mt][ks] = *(const bf16x8*)&pool[m*192 + (((ks*4+lk) ^ (m&7))*8)];
        }
        #pragma unroll
        for (int j=0; j<3; j++) {
            const int nt = wv + j*4;
            if (nt < 9) {
                bf16x8 bw[5];
                load_bfrag(W1sw, nt, lane, bw);
                #pragma unroll
                for (int mt=0; mt<2; mt++) aa[j][mt] = (f32x4){0.f,0.f,0.f,0.f};
                #pragma unroll
                for (int ks=0; ks<5; ks++)
                    #pragma unroll
                    for (int mt=0; mt<2; mt++)
                        aa[j][mt] = __builtin_amdgcn_mfma_f32_16x16x32_bf16(af[mt][ks], bw[ks], aa[j][mt], 0,0,0);
            }
        }
        #pragma unroll
        for (int mt=0; mt<2; mt++) {
            const int m = (mt+2)*16 + lm;
            #pragma unroll
            for (int ks=0; ks<5; ks++)
                af[mt][ks] = *(const bf16x8*)&pool[m*192 + (((ks*4+lk) ^ (m&7))*8)];
        }
        #pragma unroll
        for (int j=0; j<3; j++) {
            const int nt = wv + j*4;
            if (nt < 9) {
                bf16x8 bw[5];
                load_bfrag(W1sw, nt, lane, bw);
                #pragma unroll
                for (int mt=0; mt<2; mt++) ab[j][mt] = (f32x4){0.f,0.f,0.f,0.f};
                #pragma unroll
                for (int ks=0; ks<5; ks++)
                    #pragma unroll
                    for (int mt=0; mt<2; mt++)
                        ab[j][mt] = __builtin_amdgcn_mfma_f32_16x16x32_bf16(af[mt][ks], bw[ks], ab[j][mt], 0,0,0);
            }
        }
    }
    __syncthreads();   // all ea reads done; overwrite pool with hid
    #pragma unroll
    for (int j=0; j<3; j++) {
        const int nt = wv + j*4;
        if (nt < 9) {
            const int c = nt*16 + lm;
            #pragma unroll
            for (int mt=0; mt<4; mt++) {
                const f32x4 v = (mt<2) ? aa[j][mt] : ab[j][mt-2];
                #pragma unroll
                for (int r=0; r<4; r++) {
                    const int m = mt*16 + lk4 + r;
                    pool[m*192 + (((c>>3) ^ (m&7))*8) + (c&7)] = (short)f2bf(fmaxf(v[r], 0.f));
                }
            }
        }
    }
    if (t < 128) {  // bias rows k=144..159
        const int m = t >> 1, s = 18 + (t & 1);
        union { uint4 u4; unsigned short h[8]; } pk;
        pk.u4.x = pk.u4.y = pk.u4.z = pk.u4.w = 0u;
        if (s == 18) pk.h[0] = f2bf(1.f);
        *(uint4*)&pool[m*192 + ((s ^ (m&7))*8)] = pk.u4;
    }
    __syncthreads();

    // ---- each wave loads its OWN m-tile A-fragment (16 edges)
    bf16x8 ag[5];
    {
        const int m = wv*16 + lm;
        #pragma unroll
        for (int ks=0; ks<5; ks++)
            ag[ks] = *(const bf16x8*)&pool[m*192 + (((ks*4+lk) ^ (m&7))*8)];
    }
    __syncthreads();   // pool now free -> W2 stage double buffer

    auto STAGE = [&](int bufsel, int g) {
        const char* gsrc = (const char*)W2sw + (size_t)g*10240;
        char* lbase = (char*)pool + bufsel*10240;
        for (int c = wv; c < 10; c += 4) {
            __builtin_amdgcn_global_load_lds(
                (const __attribute__((address_space(1))) void*)(gsrc + c*1024 + lane*16),
                (__attribute__((address_space(3))) void*)(lbase + c*1024),
                16, 0, 0);
        }
    };

    int gstage = 1, cur = 0;
    STAGE(0, 0);
    __syncthreads();

    const int col0 = wv*16 + lk4;

    auto runpairs = [&](int count, auto&& upd) {
        for (int i = 0; i < count; i += 2) {
            if (gstage < NG) { STAGE(cur^1, gstage); ++gstage; }
            const short* tb = pool + cur*5120;
            #pragma unroll
            for (int s = 0; s < 2; ++s) {
                bf16x8 bf_[5];
                #pragma unroll
                for (int ks=0; ks<5; ks++)
                    bf_[ks] = *(const bf16x8*)&tb[s*2560 + ks*512 + lane*8];
                f32x4 a = (f32x4){0.f,0.f,0.f,0.f};
                #pragma unroll
                for (int ks=0; ks<5; ks++)
                    a = __builtin_amdgcn_mfma_f32_16x16x32_bf16(ag[ks], bf_[ks], a, 0,0,0);
                upd(i+s, a);
            }
            __syncthreads();
            cur ^= 1;
        }
    };

    float ms0[4]={0,0,0,0}, ms1[4]={0,0,0,0}, ms2[4]={0,0,0,0}, vc[4]={0,0,0,0};
    float m3[4][3] = {};
    float p3[4][3] = {};

    auto upd_ms = [&](float (&ms)[4], int i, const f32x4& a, float scale) {
        const ushort4 xw = *(const ushort4*)&xsTb[i][col0];
        ms[0] = fmaf(a[0]*scale, bf2f(xw.x), ms[0]);
        ms[1] = fmaf(a[1]*scale, bf2f(xw.y), ms[1]);
        ms[2] = fmaf(a[2]*scale, bf2f(xw.z), ms[2]);
        ms[3] = fmaf(a[3]*scale, bf2f(xw.w), ms[3]);
    };

    runpairs(48, [&](int i, const f32x4& a){ upd_ms(ms0, i, a, 1.f); });
    runpairs(48, [&](int i, const f32x4& a){ upd_ms(ms1, i, a, 1.f); });
    runpairs(48, [&](int i, const f32x4& a){ upd_ms(ms2, i, a, 1.f); });
    if (LAYER==2) {
        runpairs(10, [&](int i, const f32x4& a){
            const f32x4 u = *(const f32x4*)&uT[i][col0];
            #pragma unroll
            for (int r=0;r<4;r++) ms0[r] = fmaf(a[r]*RATIO, u[r], ms0[r]);
        });
        runpairs(10, [&](int i, const f32x4& a){
            const f32x4 u = *(const f32x4*)&uT[i][col0];
            #pragma unroll
            for (int r=0;r<4;r++) ms1[r] = fmaf(a[r]*RATIO, u[r], ms1[r]);
        });
        runpairs(10, [&](int i, const f32x4& a){
            const f32x4 u = *(const f32x4*)&uT[i][col0];
            #pragma unroll
            for (int r=0;r<4;r++) ms2[r] = fmaf(a[r]*RATIO, u[r], ms2[r]);
        });
    }
    runpairs(48, [&](int i, const f32x4& a){ upd_ms(vc, i, a, 1.f); });
    if (LAYER==2) {
        runpairs(10, [&](int i, const f32x4& a){
            #pragma unroll
            for (int d=0; d<3; d++) {
                const f32x4 x = *(const f32x4*)&xvT[i*3+d][col0];
                #pragma unroll
                for (int r=0;r<4;r++) m3[r][d] = fmaf(a[r], x[r], m3[r][d]);
            }
        });
        runpairs(10, [&](int i, const f32x4& a){
            #pragma unroll
            for (int d=0; d<3; d++) {
                const f32x4 x = *(const f32x4*)&cvT[i*3+d][col0];
                #pragma unroll
                for (int r=0;r<4;r++) p3[r][d] = fmaf(a[r], x[r], p3[r][d]);
            }
        });
    }

    // ---- message write: plain coalesced stores (NO atomics)
    const float sScale = (LAYER==1) ? INV1 : NAc;
    #pragma unroll
    for (int r=0;r<4;r++) {
        const int e = wv*16 + lk4 + r;
        const int ge = eb + e;
        if (ge < E) {
            float* mb = msg + (size_t)ge*ST;
            mb[0*16 + lm] = ms0[r]*sScale;
            mb[1*16 + lm] = ms1[r]*sScale;
            mb[2*16 + lm] = ms2[r]*sScale;
        }
    }
    if (lm < 10) {
        #pragma unroll
        for (int r=0;r<4;r++) {
            const int e = wv*16 + lk4 + r;
            const int ge = eb + e;
            if (ge < E) {
                float* mb = msg + (size_t)ge*ST;
                if (LAYER==1) {
                    const float v = vc[r]*INV1;
                    #pragma unroll
                    for (int d=0; d<3; d++)
                        mb[48 + lm*3 + d] = v*sh1l[e][d];
                } else {
                    const float v = vc[r]*NAc;
                    #pragma unroll
                    for (int d=0; d<3; d++) {
                        mb[48 + lm*3 + d] = v*sh1l[e][d] + m3[r][d]*NBc;
                        mb[78 + lm*3 + d] = p3[r][d]*C20;
                    }
                }
            }
        }
    }
}

// ----------------------------------------------------------------------------
// Gather kernels: segment-mean over CSR edge lists + residual (replace fins).
// ----------------------------------------------------------------------------
__global__ __launch_bounds__(256)
void gather1_kernel(const float* __restrict__ node_s, const float* __restrict__ msg,
                    const int* __restrict__ rowptr, const int* __restrict__ csr,
                    float* __restrict__ s1, float* __restrict__ v1, int Nn)
{
    const int p = blockIdx.x*256 + threadIdx.x;
    if (p >= Nn*78) return;
    const int n = p/78, c = p - n*78;
    const int r0 = rowptr[n], r1 = rowptr[n+1];
    float s = 0.f;
    for (int j=r0; j<r1; j++) s += msg[(size_t)csr[j]*78 + c];
    const int dgi = r1 - r0;
    s /= (float)(dgi > 1 ? dgi : 1);
    if (c < 48) s1[n*48 + c] = node_s[n*48 + c] + s;
    else        v1[n*30 + (c-48)] = s;
}

__global__ __launch_bounds__(256)
void gather2_kernel(const float* __restrict__ s1, const float* __restrict__ v1,
                    const float* __restrict__ msg,
                    const int* __restrict__ rowptr, const int* __restrict__ csr,
                    float* __restrict__ out, int Nn)
{
    const int p = blockIdx.x*256 + threadIdx.x;
    if (p >= Nn*108) return;
    const int n = p/108, c = p - n*108;
    const int r0 = rowptr[n], r1 = rowptr[n+1];
    float s = 0.f;
    for (int j=r0; j<r1; j++) s += msg[(size_t)csr[j]*108 + c];
    const int dgi = r1 - r0;
    s /= (float)(dgi > 1 ? dgi : 1);
    float base;
    if (c < 48)      base = s1[n*48 + c];
    else if (c < 78) base = v1[n*30 + (c-48)];
    else             base = 0.f;
    out[p] = base + s;
}

// ----------------------------------------------------------------------------
extern "C" void kernel_launch(void* const* d_in, const int* in_sizes, int n_in,
                              void* d_out, int out_size, void* d_ws, size_t ws_size,
                              hipStream_t stream)
{
    const float* pos    = (const float*)d_in[0];
    const float* sigma  = (const float*)d_in[1];
    const float* node_s = (const float*)d_in[2];
    const float* eW1  = (const float*)d_in[3];
    const float* eb1  = (const float*)d_in[4];
    const float* eW2  = (const float*)d_in[5];
    const float* eb2  = (const float*)d_in[6];
    const float* f1W1 = (const float*)d_in[7];
    const float* f1b1 = (const float*)d_in[8];
    const float* f1W2 = (const float*)d_in[9];
    const float* f1b2 = (const float*)d_in[10];
    const float* f2W1 = (const float*)d_in[11];
    const float* f2b1 = (const float*)d_in[12];
    const float* f2W2 = (const float*)d_in[13];
    const float* f2b2 = (const float*)d_in[14];
    const int*   ei   = (const int*)d_in[15];
    const int Nn = in_sizes[0]/3;
    const int E  = in_sizes[15]/2;
    float* out = (float*)d_out;

    char* ws = (char*)d_ws;
    float* edge_emb = (float*)ws;  ws += (size_t)E*48*sizeof(float);
    float* sh1buf   = (float*)ws;  ws += (size_t)E*4*sizeof(float);
    float* s1       = (float*)ws;  ws += (size_t)Nn*48*sizeof(float);
    float* v1       = (float*)ws;  ws += (size_t)Nn*30*sizeof(float);
    int*   deg      = (int*)ws;    ws += (size_t)Nn*sizeof(int);
    int*   rowptr   = (int*)ws;    ws += (size_t)(Nn+1)*sizeof(int);
    int*   cursor   = (int*)ws;    ws += (size_t)Nn*sizeof(int);
    int*   csr      = (int*)ws;    ws += (size_t)E*sizeof(int);
    short* W1sw     = (short*)ws;  ws += (size_t)9*5*64*8*sizeof(short);
    short* W2sw     = (short*)ws;  ws += (size_t)242*5*64*8*sizeof(short);
    float* msg      = (float*)ws;  ws += (size_t)E*108*sizeof(float);

    hipMemsetAsync(deg, 0, (size_t)Nn*sizeof(int), stream);

    edge_kernel<<<(E+3)/4, 256, 0, stream>>>(pos, sigma, ei, eW1, eb1, eW2, eb2,
                                             edge_emb, sh1buf, deg, E);
    scan_kernel<<<1, 1024, 0, stream>>>(deg, rowptr, cursor, Nn);
    place_kernel<<<(E+255)/256, 256, 0, stream>>>(ei, cursor, csr, E);

    cvt_swz<<<(9*5*64+255)/256,   256, 0, stream>>>(f1W1, f1b1, W1sw, 144, 9, 0);
    cvt_swz<<<(192*5*64+255)/256, 256, 0, stream>>>(f1W2, f1b2, W2sw, 2784, 192, 1);

    conv_kernel<1><<<(E+63)/64, 256, 0, stream>>>(edge_emb, sh1buf, ei, node_s, nullptr,
                                                  W1sw, W2sw, msg, E);
    gather1_kernel<<<((size_t)Nn*78 + 255)/256, 256, 0, stream>>>(node_s, msg, rowptr, csr,
                                                                  s1, v1, Nn);

    cvt_swz<<<(9*5*64+255)/256,   256, 0, stream>>>(f2W1, f2b1, W1sw, 144, 9, 0);
    cvt_swz<<<(242*5*64+255)/256, 256, 0, stream>>>(f2W2, f2b2, W2sw, 3464, 242, 2);

    conv_kernel<2><<<(E+63)/64, 256, 0, stream>>>(edge_emb, sh1buf, ei, s1, v1,
                                                  W1sw, W2sw, msg, E);
    gather2_kernel<<<((size_t)Nn*108 + 255)/256, 256, 0, stream>>>(s1, v1, msg, rowptr, csr,
                                                                   out, Nn);
}